// Round 12
// baseline (243.117 us; speedup 1.0000x reference)
//
#include <hip/hip_runtime.h>
#include <math.h>

#define BN 4096
#define N_PER_B 64
#define NE 16384
#define NSEL 65536
#define NET 5
#define PD 64
#define H1STR 260   // pair LDS stride (shorts): 130 dw == 2 mod 32 -> 2-way (free)
#define FSTR 264    // fstep LDS stride
#define PTILES 2    // pair tiles per block (grid 512 -> 2 blocks/CU at VGPR<=128)

typedef float f32x4 __attribute__((ext_vector_type(4)));
typedef float f32x16 __attribute__((ext_vector_type(16)));
typedef short short8 __attribute__((ext_vector_type(8)));
typedef short short4v __attribute__((ext_vector_type(4)));

__device__ __forceinline__ unsigned short f2bf(float f) {
    unsigned int u = __builtin_bit_cast(unsigned int, f);
    u += 0x7fff + ((u >> 16) & 1);          // RNE
    return (unsigned short)(u >> 16);
}
__device__ __forceinline__ float bf_lo(unsigned int u) {
    return __builtin_bit_cast(float, u << 16);
}
__device__ __forceinline__ float bf_hi(unsigned int u) {
    return __builtin_bit_cast(float, u & 0xffff0000u);
}
__device__ __forceinline__ unsigned int pack2(float a, float b) {
    return (unsigned)f2bf(a) | ((unsigned)f2bf(b) << 16);
}
// 16B fragment from 8B-aligned LDS
__device__ __forceinline__ short8 ld_frag(const unsigned short* p) {
    const short4v lo = *(const short4v*)(p);
    const short4v hi = *(const short4v*)(p + 4);
    return __builtin_shufflevector(lo, hi, 0, 1, 2, 3, 4, 5, 6, 7);
}
__device__ __forceinline__ unsigned int addrelu2(unsigned int a, unsigned int b, unsigned int c) {
    const float lo = fmaxf(bf_lo(a) + bf_lo(b) + bf_lo(c), 0.f);
    const float hi = fmaxf(bf_hi(a) + bf_hi(b) + bf_hi(c), 0.f);
    return pack2(lo, hi);
}

// ---------------------------------------------------------------------------
// CSR step 1: histogram + per-edge rank (deg zeroed by k_pre which runs 1st).
// Final position of edge e is row_start[dst] + rank[e] -> scatter needs no
// cursors and no ordering vs the scan (scan+scatter ride on fstep0).
// ---------------------------------------------------------------------------
__global__ __launch_bounds__(256) void khist_rank(const int* __restrict__ eidx,
                                                  int* __restrict__ deg,
                                                  int* __restrict__ rank)
{
    const int e = blockIdx.x * 256 + threadIdx.x;
    rank[e] = atomicAdd(&deg[eidx[NE + e]], 1);
}

// ---------------------------------------------------------------------------
// Preamble mega-kernel (independent of CSR -> launched FIRST):
//  [0,128)    weight convert/transpose fp32 [K][256] -> bf16 [256][K]
//             (blk<16 additionally zero deg; blk 0 zeroes d_out)
//  [128,192)  prop_add
//  [192,449)  Wfold = W3@W_out -> bf16 WfT[16][256] (rows 5..15 zero) + bfv
//  [449,577)  ETc[e][c] = eattr_e @ Wm_e + b_msg  (EDGE-ordered, sequential)
// ---------------------------------------------------------------------------
__global__ __launch_bounds__(256) void k_pre(
    const float* __restrict__ W_in, const float* __restrict__ W_msg,
    const float* __restrict__ W_upd, const float* __restrict__ W_add,
    const float* __restrict__ W1, const float* __restrict__ W2,
    const float* __restrict__ W3, const float* __restrict__ b3,
    const float* __restrict__ W_out, const float* __restrict__ b_out,
    const float* __restrict__ props, const float* __restrict__ W_prop,
    const float* __restrict__ b_prop, const float* __restrict__ b_add,
    const float* __restrict__ b_msg, const float* __restrict__ eattr,
    unsigned short* __restrict__ wbf, unsigned short* __restrict__ WfT,
    float* __restrict__ bfv, float* __restrict__ prop_add,
    unsigned short* __restrict__ ETc, float* __restrict__ out,
    int* __restrict__ deg)
{
    __shared__ __align__(16) char smem[16704];
    const int blk = blockIdx.x;
    const int tid = threadIdx.x;

    if (blk < 16) deg[blk * 256 + tid] = 0;   // zero histogram (16*256 = 4096)
    if (blk == 0 && tid == 0) out[0] = 0.f;   // zero loss accumulator

    if (blk < 128) {                          // ---- weight convert/transpose
        float (*s)[65] = (float(*)[65])smem;
        const int wsel = blk >> 4;
        const int sub = blk & 15;
        const float* src; unsigned short* dst; int K = 256;
        switch (wsel) {
            case 0: src = W_in;              dst = wbf;                         K = 192; break;
            case 1: src = W_msg;             dst = wbf + 49152;                 break;
            case 2: src = W_upd;             dst = wbf + 49152 + 65536;         break;
            case 3: src = W_upd + 256 * 256; dst = wbf + 49152 + 2 * 65536;     break;
            case 4: src = W_add;             dst = wbf + 49152 + 3 * 65536;     break;
            case 5: src = W1;                dst = wbf + 49152 + 4 * 65536;     break;
            case 6: src = W1 + 256 * 256;    dst = wbf + 49152 + 5 * 65536;     break;
            default: src = W2;               dst = wbf + 49152 + 6 * 65536;     break;
        }
        const int k0 = (sub >> 2) * 64;
        const int n0 = (sub & 3) * 64;
        if (k0 >= K) return;
        const int tn = tid & 63;
        const int tg = tid >> 6;
        #pragma unroll
        for (int i = 0; i < 16; ++i) {
            const int kk = tg * 16 + i;
            s[kk][tn] = src[(size_t)(k0 + kk) * 256 + n0 + tn];
        }
        __syncthreads();
        #pragma unroll
        for (int i = 0; i < 16; ++i) {
            const int nn = tg * 16 + i;
            dst[(size_t)(n0 + nn) * K + k0 + tn] = f2bf(s[tn][nn]);
        }
    } else if (blk < 192) {                   // ---- prop_add
        const int b = blk - 128;
        const float pv = props[b];
        float acc = b_add[tid];
        for (int p = 0; p < PD; ++p) {
            const float e = fmaf(pv, W_prop[p], b_prop[p]);
            acc = fmaf(e, W_add[(256 + p) * 256 + tid], acc);
        }
        prop_add[b * 256 + tid] = acc;
    } else if (blk < 449) {                   // ---- Wfold + bfv
        float* part = (float*)smem;           // [4][NET]
        const int cb = blk - 192;             // 0..256
        float acc[NET] = {0.f, 0.f, 0.f, 0.f, 0.f};
        #pragma unroll
        for (int rep = 0; rep < 2; ++rep) {
            const int j = rep * 256 + tid;
            const float wv = (cb < 256) ? W3[(size_t)cb * 512 + j] : b3[j];
            #pragma unroll
            for (int t = 0; t < NET; ++t) acc[t] = fmaf(wv, W_out[j * NET + t], acc[t]);
        }
        #pragma unroll
        for (int t = 0; t < NET; ++t)
            for (int off = 32; off >= 1; off >>= 1) acc[t] += __shfl_down(acc[t], off);
        if ((tid & 63) == 0) {
            #pragma unroll
            for (int t = 0; t < NET; ++t) part[(tid >> 6) * NET + t] = acc[t];
        }
        __syncthreads();
        if (tid == 0) {
            float s[NET];
            #pragma unroll
            for (int t = 0; t < NET; ++t)
                s[t] = part[t] + part[NET + t] + part[2 * NET + t] + part[3 * NET + t];
            if (cb < 256) {
                #pragma unroll
                for (int t = 0; t < NET; ++t) WfT[t * 256 + cb] = f2bf(s[t]);
                #pragma unroll
                for (int t = NET; t < 16; ++t) WfT[t * 256 + cb] = 0;
            } else {
                #pragma unroll
                for (int t = 0; t < NET; ++t) bfv[t] = s[t] + b_out[t];
            }
        }
    } else {                                  // ---- edge term ET (EDGE-ordered)
        float* ea = (float*)smem;             // [128*5]
        const int eb = (blk - 449) * 128;
        if (tid < 160)
            *(float4*)&ea[tid * 4] = *(const float4*)(eattr + (size_t)eb * 5 + tid * 4);
        __syncthreads();
        const float* Wme = W_msg + 256 * 256;
        const float w0 = Wme[0 * 256 + tid];
        const float w1 = Wme[1 * 256 + tid];
        const float w2 = Wme[2 * 256 + tid];
        const float w3 = Wme[3 * 256 + tid];
        const float w4 = Wme[4 * 256 + tid];
        const float bm = b_msg[tid];
        for (int i = 0; i < 128; ++i) {
            const float* a = ea + i * 5;
            float v = bm;
            v = fmaf(a[0], w0, v); v = fmaf(a[1], w1, v); v = fmaf(a[2], w2, v);
            v = fmaf(a[3], w3, v); v = fmaf(a[4], w4, v);
            ETc[(size_t)(eb + i) * 256 + tid] = f2bf(v);   // sequential rows
        }
    }
}

// ---------------------------------------------------------------------------
// Fused node step. 1024 threads = 16 waves; 16 node-rows/block.
// srcs packed: src = pk & 4095, edge = pk >> 12 (ETc is edge-ordered).
// LATENCY OVERLAP (modes 1,2): the Hg-half of phase B (Hg x WaT, 8 MFMA) and
// the WbT fragment loads do NOT depend on agg -> issued BEFORE the agg so the
// agg's cold-cache gather chain co-executes with MFMA + 24 in-flight W loads.
// acc accumulates Hg-half then Ag-half — same order as before, bit-identical.
// MODE 0 PIGGYBACK (grid 320): blocks 256..319 do the CSR scan+scatter.
// ---------------------------------------------------------------------------
__global__ __launch_bounds__(1024) void fstep(
    const float* __restrict__ x, const unsigned short* __restrict__ hbuf,
    const unsigned short* __restrict__ Pin, const unsigned short* __restrict__ ETc,
    const int* __restrict__ row_start, const int* __restrict__ srcs,
    const unsigned short* __restrict__ WaT, const unsigned short* __restrict__ WbT,
    const float* __restrict__ bias1,
    const unsigned short* __restrict__ Wp2T, const float* __restrict__ prop_add,
    const unsigned short* __restrict__ W1aT, const unsigned short* __restrict__ W1bT,
    unsigned short* __restrict__ hout, unsigned short* __restrict__ out1,
    unsigned short* __restrict__ out2, int mode,
    const int* __restrict__ eidx, const int* __restrict__ deg,
    const int* __restrict__ rank, int* __restrict__ srcs_w,
    int* __restrict__ row_start_w)
{
    __shared__ __align__(16) char smemb[4 * 16 * FSTR * 2];  // 33792 B
    __shared__ int sEdge[256];
    unsigned short* Hg  = (unsigned short*)(smemb);               // staged h
    unsigned short* Ag  = (unsigned short*)(smemb + 8448);        // agg
    unsigned short* Hs  = (unsigned short*)(smemb + 16896);       // act
    unsigned short* H2s = (unsigned short*)(smemb + 25344);       // embg
    const int tid = threadIdx.x;

    // ---- piggyback path: CSR scan + deterministic scatter (mode 0 only)
    if (mode == 0 && blockIdx.x >= 256) {
        int* sdeg = (int*)smemb;              // 4096 ints (16 KB)
        int* ssum = (int*)(smemb + 16384);    // 1024 ints (4 KB)
        const int t4 = tid * 4;
        const int4 v = *(const int4*)(deg + t4);
        const int l1 = v.x, l2 = v.x + v.y, l3 = v.x + v.y + v.z;
        ssum[tid] = l3 + v.w;
        __syncthreads();
        for (int off = 1; off < 1024; off <<= 1) {
            const int vv = ssum[tid];
            const int add = (tid >= off) ? ssum[tid - off] : 0;
            __syncthreads();
            ssum[tid] = vv + add;
            __syncthreads();
        }
        const int offset = (tid == 0) ? 0 : ssum[tid - 1];
        int4 rs;
        rs.x = offset; rs.y = offset + l1; rs.z = offset + l2; rs.w = offset + l3;
        *(int4*)(sdeg + t4) = rs;
        if (blockIdx.x == 256) {              // one block publishes row_start
            *(int4*)(row_start_w + t4) = rs;
            if (tid == 1023) row_start_w[4096] = NE;
        }
        __syncthreads();
        if (tid < 256) {
            const int e = (blockIdx.x - 256) * 256 + tid;
            const int d = eidx[NE + e];
            srcs_w[sdeg[d] + rank[e]] = eidx[e] | (e << 12);
        }
        return;
    }

    const int w = tid >> 6;          // 0..15
    const int lane = tid & 63;
    const int q = lane >> 4;
    const int tx = lane & 15;
    const int m0 = blockIdx.x * 16;
    const int col = w * 16 + tx;

    f32x4 acc = (f32x4)0.f;

    if (mode != 0) {
        // ---- stage h tile + srcs preload
        {
            const int r = tid >> 6;
            const int c4 = (tid & 63) * 4;
            *(uint2*)(Hg + r * FSTR + c4) =
                *(const uint2*)(hbuf + (size_t)(m0 + r) * 256 + c4);
        }
        const int beg0 = row_start[m0];
        const int nE = row_start[m0 + 16] - beg0;
        const bool useLds = (nE <= 256);
        if (useLds && tid < nE) sEdge[tid] = srcs[beg0 + tid];
        __syncthreads();
        const int* ep = useLds ? (const int*)sEdge : srcs;
        const int ebias = useLds ? beg0 : 0;

        // ---- WbT fragment prefetch (used after the barrier; loads ride
        //      under the agg) + Hg-half MFMA (independent of agg)
        short8 wb[8];
        #pragma unroll
        for (int s = 0; s < 8; ++s)
            wb[s] = *(const short8*)(WbT + (size_t)col * 256 + s * 32 + q * 8);
        #pragma unroll
        for (int s = 0; s < 8; ++s) {
            const int k0 = s * 32;
            const short8 af = *(const short8*)(Hg + tx * FSTR + k0 + q * 8);
            const short8 bfr = *(const short8*)(WaT + (size_t)col * 256 + k0 + q * 8);
            acc = __builtin_amdgcn_mfma_f32_16x16x32_bf16(af, bfr, acc, 0, 0, 0);
        }

        // ---- agg: wave w <-> node m0+w (4 rows in flight; cold-latency
        //      chain overlaps the MFMA + W loads above)
        {
            const int node = m0 + w;
            const int beg = row_start[node] - ebias;
            const int end = row_start[node + 1] - ebias;
            const int c = lane * 4;
            float a0 = 0.f, a1 = 0.f, a2 = 0.f, a3 = 0.f;
            int idx = beg;
            for (; idx + 3 < end; idx += 4) {
                const int k0 = ep[idx],     k1 = ep[idx + 1];
                const int k2 = ep[idx + 2], k3 = ep[idx + 3];
                const uint2 p0 = *(const uint2*)(Pin + (size_t)(k0 & 4095) * 256 + c);
                const uint2 p1 = *(const uint2*)(Pin + (size_t)(k1 & 4095) * 256 + c);
                const uint2 p2 = *(const uint2*)(Pin + (size_t)(k2 & 4095) * 256 + c);
                const uint2 p3 = *(const uint2*)(Pin + (size_t)(k3 & 4095) * 256 + c);
                const uint2 e0 = *(const uint2*)(ETc + (size_t)(k0 >> 12) * 256 + c);
                const uint2 e1 = *(const uint2*)(ETc + (size_t)(k1 >> 12) * 256 + c);
                const uint2 e2 = *(const uint2*)(ETc + (size_t)(k2 >> 12) * 256 + c);
                const uint2 e3 = *(const uint2*)(ETc + (size_t)(k3 >> 12) * 256 + c);
                a0 += fmaxf(bf_lo(p0.x) + bf_lo(e0.x), 0.f) + fmaxf(bf_lo(p1.x) + bf_lo(e1.x), 0.f)
                    + fmaxf(bf_lo(p2.x) + bf_lo(e2.x), 0.f) + fmaxf(bf_lo(p3.x) + bf_lo(e3.x), 0.f);
                a1 += fmaxf(bf_hi(p0.x) + bf_hi(e0.x), 0.f) + fmaxf(bf_hi(p1.x) + bf_hi(e1.x), 0.f)
                    + fmaxf(bf_hi(p2.x) + bf_hi(e2.x), 0.f) + fmaxf(bf_hi(p3.x) + bf_hi(e3.x), 0.f);
                a2 += fmaxf(bf_lo(p0.y) + bf_lo(e0.y), 0.f) + fmaxf(bf_lo(p1.y) + bf_lo(e1.y), 0.f)
                    + fmaxf(bf_lo(p2.y) + bf_lo(e2.y), 0.f) + fmaxf(bf_lo(p3.y) + bf_lo(e3.y), 0.f);
                a3 += fmaxf(bf_hi(p0.y) + bf_hi(e0.y), 0.f) + fmaxf(bf_hi(p1.y) + bf_hi(e1.y), 0.f)
                    + fmaxf(bf_hi(p2.y) + bf_hi(e2.y), 0.f) + fmaxf(bf_hi(p3.y) + bf_hi(e3.y), 0.f);
            }
            for (; idx < end; ++idx) {
                const int pk = ep[idx];
                const uint2 pu = *(const uint2*)(Pin + (size_t)(pk & 4095) * 256 + c);
                const uint2 eu = *(const uint2*)(ETc + (size_t)(pk >> 12) * 256 + c);
                a0 += fmaxf(bf_lo(pu.x) + bf_lo(eu.x), 0.f);
                a1 += fmaxf(bf_hi(pu.x) + bf_hi(eu.x), 0.f);
                a2 += fmaxf(bf_lo(pu.y) + bf_lo(eu.y), 0.f);
                a3 += fmaxf(bf_hi(pu.y) + bf_hi(eu.y), 0.f);
            }
            uint2 o; o.x = pack2(a0, a1); o.y = pack2(a2, a3);
            *(uint2*)(Ag + w * FSTR + c) = o;
        }
        __syncthreads();

        // ---- Ag-half MFMA (B fragments already in registers)
        #pragma unroll
        for (int s = 0; s < 8; ++s) {
            const int k0 = s * 32;
            const short8 af = *(const short8*)(Ag + tx * FSTR + k0 + q * 8);
            acc = __builtin_amdgcn_mfma_f32_16x16x32_bf16(af, wb[s], acc, 0, 0, 0);
        }
    } else {
        #pragma unroll
        for (int s = 0; s < 6; ++s) {
            const int k0 = s * 32;
            const float* ap = x + (size_t)(m0 + tx) * 192 + k0 + q * 8;
            const float4 v0 = *(const float4*)ap;
            const float4 v1 = *(const float4*)(ap + 4);
            short8 af;
            af[0] = (short)f2bf(v0.x); af[1] = (short)f2bf(v0.y);
            af[2] = (short)f2bf(v0.z); af[3] = (short)f2bf(v0.w);
            af[4] = (short)f2bf(v1.x); af[5] = (short)f2bf(v1.y);
            af[6] = (short)f2bf(v1.z); af[7] = (short)f2bf(v1.w);
            const short8 bfr = *(const short8*)(WaT + (size_t)col * 192 + k0 + q * 8);
            acc = __builtin_amdgcn_mfma_f32_16x16x32_bf16(af, bfr, acc, 0, 0, 0);
        }
    }
    {
        const float bv = bias1[col];
        #pragma unroll
        for (int r = 0; r < 4; ++r) {
            const int row = q * 4 + r;
            const unsigned short us = f2bf(fmaxf(acc[r] + bv, 0.f));
            Hs[row * FSTR + col] = us;
            if (mode < 2) hout[(size_t)(m0 + row) * 256 + col] = us;
        }
    }
    __syncthreads();

    // ---- phase C: act @ Wp2
    acc = (f32x4)0.f;
    #pragma unroll
    for (int s = 0; s < 8; ++s) {
        const int k0 = s * 32;
        const short8 af = *(const short8*)(Hs + tx * FSTR + k0 + q * 8);
        const short8 bfr = *(const short8*)(Wp2T + (size_t)col * 256 + k0 + q * 8);
        acc = __builtin_amdgcn_mfma_f32_16x16x32_bf16(af, bfr, acc, 0, 0, 0);
    }
    if (mode < 2) {
        #pragma unroll
        for (int r = 0; r < 4; ++r)
            out1[(size_t)(m0 + q * 4 + r) * 256 + col] = f2bf(acc[r]);
        return;
    }
    {
        const float pv = prop_add[(m0 >> 6) * 256 + col];
        #pragma unroll
        for (int r = 0; r < 4; ++r)
            H2s[(q * 4 + r) * FSTR + col] = f2bf(acc[r] + pv);
    }
    __syncthreads();

    // ---- phase 2b: A1 = embg@W1a, A2 = embg@W1b
    for (int which = 0; which < 2; ++which) {
        const unsigned short* WT = which ? W1bT : W1aT;
        unsigned short* op = which ? out2 : out1;
        acc = (f32x4)0.f;
        #pragma unroll
        for (int s = 0; s < 8; ++s) {
            const int k0 = s * 32;
            const short8 af = *(const short8*)(H2s + tx * FSTR + k0 + q * 8);
            const short8 bfr = *(const short8*)(WT + (size_t)col * 256 + k0 + q * 8);
            acc = __builtin_amdgcn_mfma_f32_16x16x32_bf16(af, bfr, acc, 0, 0, 0);
        }
        #pragma unroll
        for (int r = 0; r < 4; ++r)
            op[(size_t)(m0 + q * 4 + r) * 256 + col] = f2bf(acc[r]);
    }
}

// ---------------------------------------------------------------------------
// Fused pair MLP + CE, SOFTWARE-PIPELINED. Grid 512 x 512 threads; PTILES=2.
// Double-buffered sbuf/Lg. Per tile t: CE(t-1) on wave 0 runs under GEMM(t);
// gather(t+1) on waves 4-7 runs under logits(t) on waves 0-3. Same ops, same
// order -> bit-identical. LDS ~73 KB -> still 2 blocks/CU; VGPR cap 128.
// ---------------------------------------------------------------------------
__global__ __launch_bounds__(512, 2) void pair_k(
    const unsigned short* __restrict__ A1t, const unsigned short* __restrict__ A2t,
    const float* __restrict__ b1, const unsigned short* __restrict__ W2T,
    const float* __restrict__ b2, const unsigned short* __restrict__ WfT,
    const float* __restrict__ bfv,
    const int* __restrict__ sel_b, const int* __restrict__ sel_i,
    const int* __restrict__ sel_j, const int* __restrict__ golden,
    float* __restrict__ out)
{
    __shared__ __align__(16) unsigned short sbuf[2][64 * H1STR];  // H1 then H2
    __shared__ __align__(16) unsigned short b1s[256];
    __shared__ float Lg[2][64 * 8];
    __shared__ int sidx[64 * PTILES], didx[64 * PTILES], gold[64 * PTILES];

    const int tid = threadIdx.x;
    const int w = tid >> 6;          // 0..7
    const int lane = tid & 63;
    const int q = lane >> 4;
    const int tx = lane & 15;
    const int m = lane & 31;
    const int hh = lane >> 5;
    const int e0 = blockIdx.x * 64 * PTILES;

    // sel staging for all tiles (128 pairs, coalesced)
    if (tid < 64 * PTILES) {
        const int e = e0 + tid;
        const int b = sel_b[e];
        sidx[tid] = b * N_PER_B + sel_i[e];
        didx[tid] = b * N_PER_B + sel_j[e];
        gold[tid] = golden[e];
    }
    if (tid < 256) b1s[tid] = f2bf(b1[tid]);

    // ---- W2 fragment preload (once per block): 16 x short8 = 64 VGPR
    // wave w covers cols [w*32, w*32+32)
    short8 Breg[16];
    {
        const unsigned short* bb = W2T + (size_t)(w * 32 + m) * 256 + hh * 8;
        #pragma unroll
        for (int s = 0; s < 16; ++s)
            Breg[s] = *(const short8*)(bb + s * 16);
    }
    __syncthreads();

    // gather tile tt into sbuf[bb]; ngroups 32-lane groups starting at tbase
    auto GATHER = [&](int tt, int bb, int tbase, int ngroups) {
        const int hw = (tid - tbase) >> 5;
        const int rounds = 64 / ngroups;
        for (int j = 0; j < rounds; ++j) {
            const int p = j * ngroups + hw;
            const unsigned short* r1 = A1t + (size_t)sidx[tt * 64 + p] * 256 + m * 8;
            const unsigned short* r2 = A2t + (size_t)didx[tt * 64 + p] * 256 + m * 8;
            const uint4 u1 = *(const uint4*)r1;
            const uint4 u2 = *(const uint4*)r2;
            const uint4 ub = *(const uint4*)(b1s + m * 8);
            uint2 lo2, hi2;
            lo2.x = addrelu2(u1.x, u2.x, ub.x);
            lo2.y = addrelu2(u1.y, u2.y, ub.y);
            hi2.x = addrelu2(u1.z, u2.z, ub.z);
            hi2.y = addrelu2(u1.w, u2.w, ub.w);
            unsigned short* dbase = sbuf[bb] + p * H1STR + m * 8;
            *(uint2*)(dbase) = lo2;
            *(uint2*)(dbase + 4) = hi2;
        }
    };

    // CE for one tile from Lg[lb] (wave 0, tid<64)
    float total = 0.f;
    auto CE = [&](int tt, int lb) {
        float lg[NET];
        #pragma unroll
        for (int k = 0; k < NET; ++k) lg[k] = Lg[lb][tid * 8 + k];
        float mx = lg[0];
        #pragma unroll
        for (int k = 1; k < NET; ++k) mx = fmaxf(mx, lg[k]);
        float s = 0.f;
        #pragma unroll
        for (int k = 0; k < NET; ++k) s += expf(lg[k] - mx);
        float ls = mx + logf(s) - lg[gold[tt * 64 + tid]];
        #pragma unroll
        for (int off = 32; off >= 1; off >>= 1) ls += __shfl_xor(ls, off);
        total += ls;
    };

    // prologue: gather tile 0 -> buf 0 (all 16 half-wave groups)
    GATHER(0, 0, 0, 16);
    __syncthreads();

    for (int t = 0; t < PTILES; ++t) {
        const int cb = t & 1;

        // ---- CE of previous tile (wave 0) overlapped ahead of its GEMM share
        if (t > 0 && tid < 64) CE(t - 1, (t - 1) & 1);

        // ---- main GEMM: pure LDS + register-B MFMA; both pair halves
        f32x16 acc0 = (f32x16)0.f;
        f32x16 acc1 = (f32x16)0.f;
        {
            const unsigned short* a0row = sbuf[cb] + (size_t)m * H1STR + hh * 8;
            const unsigned short* a1row = a0row + 32 * H1STR;
            #pragma unroll
            for (int s = 0; s < 16; ++s) {
                const short8 af0 = ld_frag(a0row + s * 16);
                acc0 = __builtin_amdgcn_mfma_f32_32x32x16_bf16(af0, Breg[s], acc0, 0, 0, 0);
                const short8 af1 = ld_frag(a1row + s * 16);
                acc1 = __builtin_amdgcn_mfma_f32_32x32x16_bf16(af1, Breg[s], acc1, 0, 0, 0);
            }
        }
        __syncthreads();   // all H1 reads complete before overwrite

        // ---- epilogue: h2 = relu(acc + b2) -> sbuf[cb] (as H2)
        {
            const int col = w * 32 + m;
            const float bv = b2[col];
            #pragma unroll
            for (int reg = 0; reg < 16; ++reg) {
                const int prow = (reg & 3) + 8 * (reg >> 2) + 4 * hh;
                sbuf[cb][prow * H1STR + col] = f2bf(fmaxf(acc0[reg] + bv, 0.f));
                sbuf[cb][(32 + prow) * H1STR + col] = f2bf(fmaxf(acc1[reg] + bv, 0.f));
            }
        }
        __syncthreads();

        // ---- overlap: waves 0-3 logits(t) -> Lg[cb]; waves 4-7 gather(t+1)
        if (w < 4) {
            f32x4 accL = (f32x4)0.f;
            const unsigned short* a2row = sbuf[cb] + (size_t)(w * 16 + tx) * H1STR + q * 8;
            const unsigned short* bWf = WfT + (size_t)tx * 256 + q * 8;
            #pragma unroll
            for (int s = 0; s < 8; ++s) {
                const short8 af = ld_frag(a2row + s * 32);
                const short8 bfr = *(const short8*)(bWf + s * 32);
                accL = __builtin_amdgcn_mfma_f32_16x16x32_bf16(af, bfr, accL, 0, 0, 0);
            }
            if (tx < NET) {
                const float bb = bfv[tx];
                #pragma unroll
                for (int reg = 0; reg < 4; ++reg)
                    Lg[cb][(w * 16 + q * 4 + reg) * 8 + tx] = accL[reg] + bb;
            }
        } else if (t + 1 < PTILES) {
            GATHER(t + 1, (t + 1) & 1, 256, 8);
        }
        __syncthreads();
    }

    // ---- final CE (tile PTILES-1)
    if (tid < 64) CE(PTILES - 1, (PTILES - 1) & 1);
    if (tid == 0) atomicAdd(out, total * (1.0f / NSEL));
}

// ---------------------------------------------------------------------------
extern "C" void kernel_launch(void* const* d_in, const int* in_sizes, int n_in,
                              void* d_out, int out_size, void* d_ws, size_t ws_size,
                              hipStream_t stream) {
    (void)in_sizes; (void)n_in; (void)out_size; (void)ws_size;
    const float* x      = (const float*)d_in[0];
    const int*   eidx   = (const int*)d_in[1];
    const float* eattr  = (const float*)d_in[2];
    const float* props  = (const float*)d_in[3];
    const int*   sel_b  = (const int*)d_in[4];
    const int*   sel_i  = (const int*)d_in[5];
    const int*   sel_j  = (const int*)d_in[6];
    const int*   golden = (const int*)d_in[7];
    const float* W_prop = (const float*)d_in[8];
    const float* b_prop = (const float*)d_in[9];
    const float* W_in   = (const float*)d_in[10];
    const float* b_in   = (const float*)d_in[11];
    const float* W_msg  = (const float*)d_in[12];
    const float* b_msg  = (const float*)d_in[13];
    const float* W_upd  = (const float*)d_in[14];
    const float* b_upd  = (const float*)d_in[15];
    const float* W_add  = (const float*)d_in[16];
    const float* b_add  = (const float*)d_in[17];
    const float* W1     = (const float*)d_in[18];
    const float* b1     = (const float*)d_in[19];
    const float* W2     = (const float*)d_in[20];
    const float* b2     = (const float*)d_in[21];
    const float* W3     = (const float*)d_in[22];
    const float* b3     = (const float*)d_in[23];
    const float* W_out  = (const float*)d_in[24];
    const float* b_out  = (const float*)d_in[25];

    const size_t SEG = (size_t)BN * 256;
    unsigned short* P0   = (unsigned short*)d_ws;   // P even rounds; final A1
    unsigned short* P1   = P0 + SEG;                // P odd rounds
    unsigned short* hA   = P1 + SEG;                // h double-buffer; final A2
    unsigned short* hB   = hA + SEG;
    unsigned short* ETc  = hB + SEG;                // [NE][256] EDGE-ordered
    unsigned short* wbf  = ETc + (size_t)NE * 256;
    unsigned short* W_inT  = wbf;                   // [256][192]
    unsigned short* WmT    = wbf + 49152;
    unsigned short* WuaT   = WmT + 65536;
    unsigned short* WubT   = WuaT + 65536;
    unsigned short* W_addT = WubT + 65536;
    unsigned short* W1aT   = W_addT + 65536;
    unsigned short* W1bT   = W1aT + 65536;
    unsigned short* W2T    = W1bT + 65536;
    unsigned short* WfT    = W2T + 65536;           // [16][256]
    float* prop_add = (float*)(WfT + 4096);         // [64][256]
    float* bfv = prop_add + 64 * 256;               // [16]
    int* row_start = (int*)(bfv + 16);              // [4104]
    int* srcs      = row_start + 4104;              // [NE] packed src|e<<12
    int* deg       = srcs + NE;                     // [4096]
    int* rank      = deg + 4096;                    // [NE]

    // k_pre independent of CSR: runs first, zeroes deg and d_out
    k_pre<<<577, 256, 0, stream>>>(W_in, W_msg, W_upd, W_add, W1, W2, W3, b3,
                                   W_out, b_out, props, W_prop, b_prop, b_add,
                                   b_msg, eattr, wbf, WfT, bfv, prop_add,
                                   ETc, (float*)d_out, deg);
    khist_rank<<<NE / 256, 256, 0, stream>>>(eidx, deg, rank);

    // round 0 (grid 320): blocks 0-255 = h0/P0; blocks 256-319 = CSR scan+scatter
    fstep<<<320, 1024, 0, stream>>>(x, nullptr, nullptr, ETc, row_start, srcs,
                                    W_inT, nullptr, b_in, WmT, nullptr, nullptr, nullptr,
                                    hA, P0, nullptr, 0,
                                    eidx, deg, rank, srcs, row_start);
    // rounds 1..3: agg(P) -> h' -> P'
    fstep<<<256, 1024, 0, stream>>>(nullptr, hA, P0, ETc, row_start, srcs,
                                    WuaT, WubT, b_upd, WmT, nullptr, nullptr, nullptr,
                                    hB, P1, nullptr, 1,
                                    nullptr, nullptr, nullptr, nullptr, nullptr);
    fstep<<<256, 1024, 0, stream>>>(nullptr, hB, P1, ETc, row_start, srcs,
                                    WuaT, WubT, b_upd, WmT, nullptr, nullptr, nullptr,
                                    hA, P0, nullptr, 1,
                                    nullptr, nullptr, nullptr, nullptr, nullptr);
    fstep<<<256, 1024, 0, stream>>>(nullptr, hA, P0, ETc, row_start, srcs,
                                    WuaT, WubT, b_upd, WmT, nullptr, nullptr, nullptr,
                                    hB, P1, nullptr, 1,
                                    nullptr, nullptr, nullptr, nullptr, nullptr);
    // final: agg(P1) -> h4 -> embg -> A1 (P0), A2 (hA)
    fstep<<<256, 1024, 0, stream>>>(nullptr, hB, P1, ETc, row_start, srcs,
                                    WuaT, WubT, b_upd, W_addT, prop_add, W1aT, W1bT,
                                    nullptr, P0, hA, 2,
                                    nullptr, nullptr, nullptr, nullptr, nullptr);

    pair_k<<<NSEL / (64 * PTILES), 512, 0, stream>>>(P0, hA, b1, W2T, b2, WfT, bfv,
                                    sel_b, sel_i, sel_j, golden, (float*)d_out);
}

// Round 13
// 237.210 us; speedup vs baseline: 1.0249x; 1.0249x over previous
//
#include <hip/hip_runtime.h>
#include <math.h>

#define BN 4096
#define N_PER_B 64
#define NE 16384
#define NSEL 65536
#define NET 5
#define PD 64
#define H1STR 260   // pair LDS stride (shorts): 130 dw == 2 mod 32 -> 2-way (free)
#define FSTR 264    // fstep LDS stride
#define PTILES 2    // pair tiles per block (grid 512 -> 2 blocks/CU at VGPR<=128)

typedef float f32x4 __attribute__((ext_vector_type(4)));
typedef float f32x16 __attribute__((ext_vector_type(16)));
typedef short short8 __attribute__((ext_vector_type(8)));
typedef short short4v __attribute__((ext_vector_type(4)));

__device__ __forceinline__ unsigned short f2bf(float f) {
    unsigned int u = __builtin_bit_cast(unsigned int, f);
    u += 0x7fff + ((u >> 16) & 1);          // RNE
    return (unsigned short)(u >> 16);
}
__device__ __forceinline__ float bf_lo(unsigned int u) {
    return __builtin_bit_cast(float, u << 16);
}
__device__ __forceinline__ float bf_hi(unsigned int u) {
    return __builtin_bit_cast(float, u & 0xffff0000u);
}
__device__ __forceinline__ unsigned int pack2(float a, float b) {
    return (unsigned)f2bf(a) | ((unsigned)f2bf(b) << 16);
}
// 16B fragment from 8B-aligned LDS
__device__ __forceinline__ short8 ld_frag(const unsigned short* p) {
    const short4v lo = *(const short4v*)(p);
    const short4v hi = *(const short4v*)(p + 4);
    return __builtin_shufflevector(lo, hi, 0, 1, 2, 3, 4, 5, 6, 7);
}
__device__ __forceinline__ unsigned int addrelu2(unsigned int a, unsigned int b, unsigned int c) {
    const float lo = fmaxf(bf_lo(a) + bf_lo(b) + bf_lo(c), 0.f);
    const float hi = fmaxf(bf_hi(a) + bf_hi(b) + bf_hi(c), 0.f);
    return pack2(lo, hi);
}

// ---------------------------------------------------------------------------
// CSR step 1: histogram + per-edge rank (deg zeroed by k_pre which runs 1st).
// Final position of edge e is row_start[dst] + rank[e] -> scatter needs no
// cursors and no ordering vs the scan (scan+scatter ride on fstep0).
// ---------------------------------------------------------------------------
__global__ __launch_bounds__(256) void khist_rank(const int* __restrict__ eidx,
                                                  int* __restrict__ deg,
                                                  int* __restrict__ rank)
{
    const int e = blockIdx.x * 256 + threadIdx.x;
    rank[e] = atomicAdd(&deg[eidx[NE + e]], 1);
}

// ---------------------------------------------------------------------------
// Preamble mega-kernel (independent of CSR -> launched FIRST):
//  [0,128)    weight convert/transpose fp32 [K][256] -> bf16 [256][K]
//             (blk<16 additionally zero deg; blk 0 zeroes d_out)
//  [128,192)  prop_add
//  [192,449)  Wfold = W3@W_out -> bf16 WfT[16][256] (rows 5..15 zero) + bfv
//  [449,577)  ETc[e][c] = eattr_e @ Wm_e + b_msg  (EDGE-ordered, sequential)
// ---------------------------------------------------------------------------
__global__ __launch_bounds__(256) void k_pre(
    const float* __restrict__ W_in, const float* __restrict__ W_msg,
    const float* __restrict__ W_upd, const float* __restrict__ W_add,
    const float* __restrict__ W1, const float* __restrict__ W2,
    const float* __restrict__ W3, const float* __restrict__ b3,
    const float* __restrict__ W_out, const float* __restrict__ b_out,
    const float* __restrict__ props, const float* __restrict__ W_prop,
    const float* __restrict__ b_prop, const float* __restrict__ b_add,
    const float* __restrict__ b_msg, const float* __restrict__ eattr,
    unsigned short* __restrict__ wbf, unsigned short* __restrict__ WfT,
    float* __restrict__ bfv, float* __restrict__ prop_add,
    unsigned short* __restrict__ ETc, float* __restrict__ out,
    int* __restrict__ deg)
{
    __shared__ __align__(16) char smem[16704];
    const int blk = blockIdx.x;
    const int tid = threadIdx.x;

    if (blk < 16) deg[blk * 256 + tid] = 0;   // zero histogram (16*256 = 4096)
    if (blk == 0 && tid == 0) out[0] = 0.f;   // zero loss accumulator

    if (blk < 128) {                          // ---- weight convert/transpose
        float (*s)[65] = (float(*)[65])smem;
        const int wsel = blk >> 4;
        const int sub = blk & 15;
        const float* src; unsigned short* dst; int K = 256;
        switch (wsel) {
            case 0: src = W_in;              dst = wbf;                         K = 192; break;
            case 1: src = W_msg;             dst = wbf + 49152;                 break;
            case 2: src = W_upd;             dst = wbf + 49152 + 65536;         break;
            case 3: src = W_upd + 256 * 256; dst = wbf + 49152 + 2 * 65536;     break;
            case 4: src = W_add;             dst = wbf + 49152 + 3 * 65536;     break;
            case 5: src = W1;                dst = wbf + 49152 + 4 * 65536;     break;
            case 6: src = W1 + 256 * 256;    dst = wbf + 49152 + 5 * 65536;     break;
            default: src = W2;               dst = wbf + 49152 + 6 * 65536;     break;
        }
        const int k0 = (sub >> 2) * 64;
        const int n0 = (sub & 3) * 64;
        if (k0 >= K) return;
        const int tn = tid & 63;
        const int tg = tid >> 6;
        #pragma unroll
        for (int i = 0; i < 16; ++i) {
            const int kk = tg * 16 + i;
            s[kk][tn] = src[(size_t)(k0 + kk) * 256 + n0 + tn];
        }
        __syncthreads();
        #pragma unroll
        for (int i = 0; i < 16; ++i) {
            const int nn = tg * 16 + i;
            dst[(size_t)(n0 + nn) * K + k0 + tn] = f2bf(s[tn][nn]);
        }
    } else if (blk < 192) {                   // ---- prop_add
        const int b = blk - 128;
        const float pv = props[b];
        float acc = b_add[tid];
        for (int p = 0; p < PD; ++p) {
            const float e = fmaf(pv, W_prop[p], b_prop[p]);
            acc = fmaf(e, W_add[(256 + p) * 256 + tid], acc);
        }
        prop_add[b * 256 + tid] = acc;
    } else if (blk < 449) {                   // ---- Wfold + bfv
        float* part = (float*)smem;           // [4][NET]
        const int cb = blk - 192;             // 0..256
        float acc[NET] = {0.f, 0.f, 0.f, 0.f, 0.f};
        #pragma unroll
        for (int rep = 0; rep < 2; ++rep) {
            const int j = rep * 256 + tid;
            const float wv = (cb < 256) ? W3[(size_t)cb * 512 + j] : b3[j];
            #pragma unroll
            for (int t = 0; t < NET; ++t) acc[t] = fmaf(wv, W_out[j * NET + t], acc[t]);
        }
        #pragma unroll
        for (int t = 0; t < NET; ++t)
            for (int off = 32; off >= 1; off >>= 1) acc[t] += __shfl_down(acc[t], off);
        if ((tid & 63) == 0) {
            #pragma unroll
            for (int t = 0; t < NET; ++t) part[(tid >> 6) * NET + t] = acc[t];
        }
        __syncthreads();
        if (tid == 0) {
            float s[NET];
            #pragma unroll
            for (int t = 0; t < NET; ++t)
                s[t] = part[t] + part[NET + t] + part[2 * NET + t] + part[3 * NET + t];
            if (cb < 256) {
                #pragma unroll
                for (int t = 0; t < NET; ++t) WfT[t * 256 + cb] = f2bf(s[t]);
                #pragma unroll
                for (int t = NET; t < 16; ++t) WfT[t * 256 + cb] = 0;
            } else {
                #pragma unroll
                for (int t = 0; t < NET; ++t) bfv[t] = s[t] + b_out[t];
            }
        }
    } else {                                  // ---- edge term ET (EDGE-ordered)
        float* ea = (float*)smem;             // [128*5]
        const int eb = (blk - 449) * 128;
        if (tid < 160)
            *(float4*)&ea[tid * 4] = *(const float4*)(eattr + (size_t)eb * 5 + tid * 4);
        __syncthreads();
        const float* Wme = W_msg + 256 * 256;
        const float w0 = Wme[0 * 256 + tid];
        const float w1 = Wme[1 * 256 + tid];
        const float w2 = Wme[2 * 256 + tid];
        const float w3 = Wme[3 * 256 + tid];
        const float w4 = Wme[4 * 256 + tid];
        const float bm = b_msg[tid];
        for (int i = 0; i < 128; ++i) {
            const float* a = ea + i * 5;
            float v = bm;
            v = fmaf(a[0], w0, v); v = fmaf(a[1], w1, v); v = fmaf(a[2], w2, v);
            v = fmaf(a[3], w3, v); v = fmaf(a[4], w4, v);
            ETc[(size_t)(eb + i) * 256 + tid] = f2bf(v);   // sequential rows
        }
    }
}

// ---------------------------------------------------------------------------
// Fused node step: agg (CSR gather, 4 rows in flight, LDS-preloaded indices)
// + act GEMM + 2nd GEMM. 1024 threads = 16 waves; 16 node-rows/block.
// srcs packed: src = pk & 4095, edge = pk >> 12 (ETc is edge-ordered).
// Block's CSR slice [row_start[m0], row_start[m0+16]) is contiguous and
// almost always <=256 entries -> preloaded to sEdge; indices rebased by
// ebias so every sEdge access is in [0, nE) (no UB pointer arithmetic).
// NOTE (R12 lesson): at 16 waves/CU the agg chain is already TLP-overlapped;
// intra-wave reordering that delays its start regresses. Keep agg first.
// MODE 0 PIGGYBACK (grid 320): blocks 256..319 do the CSR scan+scatter.
// ---------------------------------------------------------------------------
__global__ __launch_bounds__(1024) void fstep(
    const float* __restrict__ x, const unsigned short* __restrict__ hbuf,
    const unsigned short* __restrict__ Pin, const unsigned short* __restrict__ ETc,
    const int* __restrict__ row_start, const int* __restrict__ srcs,
    const unsigned short* __restrict__ WaT, const unsigned short* __restrict__ WbT,
    const float* __restrict__ bias1,
    const unsigned short* __restrict__ Wp2T, const float* __restrict__ prop_add,
    const unsigned short* __restrict__ W1aT, const unsigned short* __restrict__ W1bT,
    unsigned short* __restrict__ hout, unsigned short* __restrict__ out1,
    unsigned short* __restrict__ out2, int mode,
    const int* __restrict__ eidx, const int* __restrict__ deg,
    const int* __restrict__ rank, int* __restrict__ srcs_w,
    int* __restrict__ row_start_w)
{
    __shared__ __align__(16) char smemb[4 * 16 * FSTR * 2];  // 33792 B
    __shared__ int sEdge[256];
    unsigned short* Hg  = (unsigned short*)(smemb);               // staged h
    unsigned short* Ag  = (unsigned short*)(smemb + 8448);        // agg
    unsigned short* Hs  = (unsigned short*)(smemb + 16896);       // act
    unsigned short* H2s = (unsigned short*)(smemb + 25344);       // embg
    const int tid = threadIdx.x;

    // ---- piggyback path: CSR scan + deterministic scatter (mode 0 only)
    if (mode == 0 && blockIdx.x >= 256) {
        int* sdeg = (int*)smemb;              // 4096 ints (16 KB)
        int* ssum = (int*)(smemb + 16384);    // 1024 ints (4 KB)
        const int t4 = tid * 4;
        const int4 v = *(const int4*)(deg + t4);
        const int l1 = v.x, l2 = v.x + v.y, l3 = v.x + v.y + v.z;
        ssum[tid] = l3 + v.w;
        __syncthreads();
        for (int off = 1; off < 1024; off <<= 1) {
            const int vv = ssum[tid];
            const int add = (tid >= off) ? ssum[tid - off] : 0;
            __syncthreads();
            ssum[tid] = vv + add;
            __syncthreads();
        }
        const int offset = (tid == 0) ? 0 : ssum[tid - 1];
        int4 rs;
        rs.x = offset; rs.y = offset + l1; rs.z = offset + l2; rs.w = offset + l3;
        *(int4*)(sdeg + t4) = rs;
        if (blockIdx.x == 256) {              // one block publishes row_start
            *(int4*)(row_start_w + t4) = rs;
            if (tid == 1023) row_start_w[4096] = NE;
        }
        __syncthreads();
        if (tid < 256) {
            const int e = (blockIdx.x - 256) * 256 + tid;
            const int d = eidx[NE + e];
            srcs_w[sdeg[d] + rank[e]] = eidx[e] | (e << 12);
        }
        return;
    }

    const int w = tid >> 6;          // 0..15
    const int lane = tid & 63;
    const int q = lane >> 4;
    const int tx = lane & 15;
    const int m0 = blockIdx.x * 16;
    const int col = w * 16 + tx;

    // ---- phase A: stage h tile + srcs preload + agg tile (modes 1,2)
    if (mode != 0) {
        {
            const int r = tid >> 6;
            const int c4 = (tid & 63) * 4;
            *(uint2*)(Hg + r * FSTR + c4) =
                *(const uint2*)(hbuf + (size_t)(m0 + r) * 256 + c4);
        }
        const int beg0 = row_start[m0];
        const int nE = row_start[m0 + 16] - beg0;
        const bool useLds = (nE <= 256);
        if (useLds && tid < nE) sEdge[tid] = srcs[beg0 + tid];
        __syncthreads();
        const int* ep = useLds ? (const int*)sEdge : srcs;
        const int ebias = useLds ? beg0 : 0;
        {
            const int node = m0 + w;          // wave w <-> node row w
            const int beg = row_start[node] - ebias;
            const int end = row_start[node + 1] - ebias;
            const int c = lane * 4;
            float a0 = 0.f, a1 = 0.f, a2 = 0.f, a3 = 0.f;
            int idx = beg;
            for (; idx + 3 < end; idx += 4) {   // 4 rows in flight
                const int k0 = ep[idx],     k1 = ep[idx + 1];
                const int k2 = ep[idx + 2], k3 = ep[idx + 3];
                const uint2 p0 = *(const uint2*)(Pin + (size_t)(k0 & 4095) * 256 + c);
                const uint2 p1 = *(const uint2*)(Pin + (size_t)(k1 & 4095) * 256 + c);
                const uint2 p2 = *(const uint2*)(Pin + (size_t)(k2 & 4095) * 256 + c);
                const uint2 p3 = *(const uint2*)(Pin + (size_t)(k3 & 4095) * 256 + c);
                const uint2 e0 = *(const uint2*)(ETc + (size_t)(k0 >> 12) * 256 + c);
                const uint2 e1 = *(const uint2*)(ETc + (size_t)(k1 >> 12) * 256 + c);
                const uint2 e2 = *(const uint2*)(ETc + (size_t)(k2 >> 12) * 256 + c);
                const uint2 e3 = *(const uint2*)(ETc + (size_t)(k3 >> 12) * 256 + c);
                a0 += fmaxf(bf_lo(p0.x) + bf_lo(e0.x), 0.f) + fmaxf(bf_lo(p1.x) + bf_lo(e1.x), 0.f)
                    + fmaxf(bf_lo(p2.x) + bf_lo(e2.x), 0.f) + fmaxf(bf_lo(p3.x) + bf_lo(e3.x), 0.f);
                a1 += fmaxf(bf_hi(p0.x) + bf_hi(e0.x), 0.f) + fmaxf(bf_hi(p1.x) + bf_hi(e1.x), 0.f)
                    + fmaxf(bf_hi(p2.x) + bf_hi(e2.x), 0.f) + fmaxf(bf_hi(p3.x) + bf_hi(e3.x), 0.f);
                a2 += fmaxf(bf_lo(p0.y) + bf_lo(e0.y), 0.f) + fmaxf(bf_lo(p1.y) + bf_lo(e1.y), 0.f)
                    + fmaxf(bf_lo(p2.y) + bf_lo(e2.y), 0.f) + fmaxf(bf_lo(p3.y) + bf_lo(e3.y), 0.f);
                a3 += fmaxf(bf_hi(p0.y) + bf_hi(e0.y), 0.f) + fmaxf(bf_hi(p1.y) + bf_hi(e1.y), 0.f)
                    + fmaxf(bf_hi(p2.y) + bf_hi(e2.y), 0.f) + fmaxf(bf_hi(p3.y) + bf_hi(e3.y), 0.f);
            }
            for (; idx < end; ++idx) {
                const int pk = ep[idx];
                const uint2 pu = *(const uint2*)(Pin + (size_t)(pk & 4095) * 256 + c);
                const uint2 eu = *(const uint2*)(ETc + (size_t)(pk >> 12) * 256 + c);
                a0 += fmaxf(bf_lo(pu.x) + bf_lo(eu.x), 0.f);
                a1 += fmaxf(bf_hi(pu.x) + bf_hi(eu.x), 0.f);
                a2 += fmaxf(bf_lo(pu.y) + bf_lo(eu.y), 0.f);
                a3 += fmaxf(bf_hi(pu.y) + bf_hi(eu.y), 0.f);
            }
            uint2 o; o.x = pack2(a0, a1); o.y = pack2(a2, a3);
            *(uint2*)(Ag + w * FSTR + c) = o;
        }
        __syncthreads();
    }

    // ---- phase B: act = relu(A@W + b), wave w -> one 16-col tile
    f32x4 acc = (f32x4)0.f;
    if (mode == 0) {
        #pragma unroll
        for (int s = 0; s < 6; ++s) {
            const int k0 = s * 32;
            const float* ap = x + (size_t)(m0 + tx) * 192 + k0 + q * 8;
            const float4 v0 = *(const float4*)ap;
            const float4 v1 = *(const float4*)(ap + 4);
            short8 af;
            af[0] = (short)f2bf(v0.x); af[1] = (short)f2bf(v0.y);
            af[2] = (short)f2bf(v0.z); af[3] = (short)f2bf(v0.w);
            af[4] = (short)f2bf(v1.x); af[5] = (short)f2bf(v1.y);
            af[6] = (short)f2bf(v1.z); af[7] = (short)f2bf(v1.w);
            const short8 bfr = *(const short8*)(WaT + (size_t)col * 192 + k0 + q * 8);
            acc = __builtin_amdgcn_mfma_f32_16x16x32_bf16(af, bfr, acc, 0, 0, 0);
        }
    } else {
        #pragma unroll
        for (int s = 0; s < 8; ++s) {
            const int k0 = s * 32;
            const short8 af = *(const short8*)(Hg + tx * FSTR + k0 + q * 8);
            const short8 bfr = *(const short8*)(WaT + (size_t)col * 256 + k0 + q * 8);
            acc = __builtin_amdgcn_mfma_f32_16x16x32_bf16(af, bfr, acc, 0, 0, 0);
        }
        #pragma unroll
        for (int s = 0; s < 8; ++s) {
            const int k0 = s * 32;
            const short8 af = *(const short8*)(Ag + tx * FSTR + k0 + q * 8);
            const short8 bfr = *(const short8*)(WbT + (size_t)col * 256 + k0 + q * 8);
            acc = __builtin_amdgcn_mfma_f32_16x16x32_bf16(af, bfr, acc, 0, 0, 0);
        }
    }
    {
        const float bv = bias1[col];
        #pragma unroll
        for (int r = 0; r < 4; ++r) {
            const int row = q * 4 + r;
            const unsigned short us = f2bf(fmaxf(acc[r] + bv, 0.f));
            Hs[row * FSTR + col] = us;
            if (mode < 2) hout[(size_t)(m0 + row) * 256 + col] = us;
        }
    }
    __syncthreads();

    // ---- phase C: act @ Wp2
    acc = (f32x4)0.f;
    #pragma unroll
    for (int s = 0; s < 8; ++s) {
        const int k0 = s * 32;
        const short8 af = *(const short8*)(Hs + tx * FSTR + k0 + q * 8);
        const short8 bfr = *(const short8*)(Wp2T + (size_t)col * 256 + k0 + q * 8);
        acc = __builtin_amdgcn_mfma_f32_16x16x32_bf16(af, bfr, acc, 0, 0, 0);
    }
    if (mode < 2) {
        #pragma unroll
        for (int r = 0; r < 4; ++r)
            out1[(size_t)(m0 + q * 4 + r) * 256 + col] = f2bf(acc[r]);
        return;
    }
    {
        const float pv = prop_add[(m0 >> 6) * 256 + col];
        #pragma unroll
        for (int r = 0; r < 4; ++r)
            H2s[(q * 4 + r) * FSTR + col] = f2bf(acc[r] + pv);
    }
    __syncthreads();

    // ---- phase 2b: A1 = embg@W1a, A2 = embg@W1b
    for (int which = 0; which < 2; ++which) {
        const unsigned short* WT = which ? W1bT : W1aT;
        unsigned short* op = which ? out2 : out1;
        acc = (f32x4)0.f;
        #pragma unroll
        for (int s = 0; s < 8; ++s) {
            const int k0 = s * 32;
            const short8 af = *(const short8*)(H2s + tx * FSTR + k0 + q * 8);
            const short8 bfr = *(const short8*)(WT + (size_t)col * 256 + k0 + q * 8);
            acc = __builtin_amdgcn_mfma_f32_16x16x32_bf16(af, bfr, acc, 0, 0, 0);
        }
        #pragma unroll
        for (int r = 0; r < 4; ++r)
            op[(size_t)(m0 + q * 4 + r) * 256 + col] = f2bf(acc[r]);
    }
}

// ---------------------------------------------------------------------------
// Fused pair MLP + CE, SOFTWARE-PIPELINED. Grid 512 x 512 threads; PTILES=2.
// Double-buffered sbuf/Lg. Per tile t: CE(t-1) on wave 0 runs under GEMM(t);
// gather(t+1) on waves 4-7 runs under logits(t) on waves 0-3. Same ops, same
// order -> bit-identical. LDS ~73 KB -> still 2 blocks/CU; VGPR cap 128.
// ---------------------------------------------------------------------------
__global__ __launch_bounds__(512, 2) void pair_k(
    const unsigned short* __restrict__ A1t, const unsigned short* __restrict__ A2t,
    const float* __restrict__ b1, const unsigned short* __restrict__ W2T,
    const float* __restrict__ b2, const unsigned short* __restrict__ WfT,
    const float* __restrict__ bfv,
    const int* __restrict__ sel_b, const int* __restrict__ sel_i,
    const int* __restrict__ sel_j, const int* __restrict__ golden,
    float* __restrict__ out)
{
    __shared__ __align__(16) unsigned short sbuf[2][64 * H1STR];  // H1 then H2
    __shared__ __align__(16) unsigned short b1s[256];
    __shared__ float Lg[2][64 * 8];
    __shared__ int sidx[64 * PTILES], didx[64 * PTILES], gold[64 * PTILES];

    const int tid = threadIdx.x;
    const int w = tid >> 6;          // 0..7
    const int lane = tid & 63;
    const int q = lane >> 4;
    const int tx = lane & 15;
    const int m = lane & 31;
    const int hh = lane >> 5;
    const int e0 = blockIdx.x * 64 * PTILES;

    // sel staging for all tiles (128 pairs, coalesced)
    if (tid < 64 * PTILES) {
        const int e = e0 + tid;
        const int b = sel_b[e];
        sidx[tid] = b * N_PER_B + sel_i[e];
        didx[tid] = b * N_PER_B + sel_j[e];
        gold[tid] = golden[e];
    }
    if (tid < 256) b1s[tid] = f2bf(b1[tid]);

    // ---- W2 fragment preload (once per block): 16 x short8 = 64 VGPR
    // wave w covers cols [w*32, w*32+32)
    short8 Breg[16];
    {
        const unsigned short* bb = W2T + (size_t)(w * 32 + m) * 256 + hh * 8;
        #pragma unroll
        for (int s = 0; s < 16; ++s)
            Breg[s] = *(const short8*)(bb + s * 16);
    }
    __syncthreads();

    // gather tile tt into sbuf[bb]; ngroups 32-lane groups starting at tbase
    auto GATHER = [&](int tt, int bb, int tbase, int ngroups) {
        const int hw = (tid - tbase) >> 5;
        const int rounds = 64 / ngroups;
        for (int j = 0; j < rounds; ++j) {
            const int p = j * ngroups + hw;
            const unsigned short* r1 = A1t + (size_t)sidx[tt * 64 + p] * 256 + m * 8;
            const unsigned short* r2 = A2t + (size_t)didx[tt * 64 + p] * 256 + m * 8;
            const uint4 u1 = *(const uint4*)r1;
            const uint4 u2 = *(const uint4*)r2;
            const uint4 ub = *(const uint4*)(b1s + m * 8);
            uint2 lo2, hi2;
            lo2.x = addrelu2(u1.x, u2.x, ub.x);
            lo2.y = addrelu2(u1.y, u2.y, ub.y);
            hi2.x = addrelu2(u1.z, u2.z, ub.z);
            hi2.y = addrelu2(u1.w, u2.w, ub.w);
            unsigned short* dbase = sbuf[bb] + p * H1STR + m * 8;
            *(uint2*)(dbase) = lo2;
            *(uint2*)(dbase + 4) = hi2;
        }
    };

    // CE for one tile from Lg[lb] (wave 0, tid<64)
    float total = 0.f;
    auto CE = [&](int tt, int lb) {
        float lg[NET];
        #pragma unroll
        for (int k = 0; k < NET; ++k) lg[k] = Lg[lb][tid * 8 + k];
        float mx = lg[0];
        #pragma unroll
        for (int k = 1; k < NET; ++k) mx = fmaxf(mx, lg[k]);
        float s = 0.f;
        #pragma unroll
        for (int k = 0; k < NET; ++k) s += expf(lg[k] - mx);
        float ls = mx + logf(s) - lg[gold[tt * 64 + tid]];
        #pragma unroll
        for (int off = 32; off >= 1; off >>= 1) ls += __shfl_xor(ls, off);
        total += ls;
    };

    // prologue: gather tile 0 -> buf 0 (all 16 half-wave groups)
    GATHER(0, 0, 0, 16);
    __syncthreads();

    for (int t = 0; t < PTILES; ++t) {
        const int cb = t & 1;

        // ---- CE of previous tile (wave 0) overlapped ahead of its GEMM share
        if (t > 0 && tid < 64) CE(t - 1, (t - 1) & 1);

        // ---- main GEMM: pure LDS + register-B MFMA; both pair halves
        f32x16 acc0 = (f32x16)0.f;
        f32x16 acc1 = (f32x16)0.f;
        {
            const unsigned short* a0row = sbuf[cb] + (size_t)m * H1STR + hh * 8;
            const unsigned short* a1row = a0row + 32 * H1STR;
            #pragma unroll
            for (int s = 0; s < 16; ++s) {
                const short8 af0 = ld_frag(a0row + s * 16);
                acc0 = __builtin_amdgcn_mfma_f32_32x32x16_bf16(af0, Breg[s], acc0, 0, 0, 0);
                const short8 af1 = ld_frag(a1row + s * 16);
                acc1 = __builtin_amdgcn_mfma_f32_32x32x16_bf16(af1, Breg[s], acc1, 0, 0, 0);
            }
        }
        __syncthreads();   // all H1 reads complete before overwrite

        // ---- epilogue: h2 = relu(acc + b2) -> sbuf[cb] (as H2)
        {
            const int col = w * 32 + m;
            const float bv = b2[col];
            #pragma unroll
            for (int reg = 0; reg < 16; ++reg) {
                const int prow = (reg & 3) + 8 * (reg >> 2) + 4 * hh;
                sbuf[cb][prow * H1STR + col] = f2bf(fmaxf(acc0[reg] + bv, 0.f));
                sbuf[cb][(32 + prow) * H1STR + col] = f2bf(fmaxf(acc1[reg] + bv, 0.f));
            }
        }
        __syncthreads();

        // ---- overlap: waves 0-3 logits(t) -> Lg[cb]; waves 4-7 gather(t+1)
        if (w < 4) {
            f32x4 accL = (f32x4)0.f;
            const unsigned short* a2row = sbuf[cb] + (size_t)(w * 16 + tx) * H1STR + q * 8;
            const unsigned short* bWf = WfT + (size_t)tx * 256 + q * 8;
            #pragma unroll
            for (int s = 0; s < 8; ++s) {
                const short8 af = ld_frag(a2row + s * 32);
                const short8 bfr = *(const short8*)(bWf + s * 32);
                accL = __builtin_amdgcn_mfma_f32_16x16x32_bf16(af, bfr, accL, 0, 0, 0);
            }
            if (tx < NET) {
                const float bb = bfv[tx];
                #pragma unroll
                for (int reg = 0; reg < 4; ++reg)
                    Lg[cb][(w * 16 + q * 4 + reg) * 8 + tx] = accL[reg] + bb;
            }
        } else if (t + 1 < PTILES) {
            GATHER(t + 1, (t + 1) & 1, 256, 8);
        }
        __syncthreads();
    }

    // ---- final CE (tile PTILES-1)
    if (tid < 64) CE(PTILES - 1, (PTILES - 1) & 1);
    if (tid == 0) atomicAdd(out, total * (1.0f / NSEL));
}

// ---------------------------------------------------------------------------
extern "C" void kernel_launch(void* const* d_in, const int* in_sizes, int n_in,
                              void* d_out, int out_size, void* d_ws, size_t ws_size,
                              hipStream_t stream) {
    (void)in_sizes; (void)n_in; (void)out_size; (void)ws_size;
    const float* x      = (const float*)d_in[0];
    const int*   eidx   = (const int*)d_in[1];
    const float* eattr  = (const float*)d_in[2];
    const float* props  = (const float*)d_in[3];
    const int*   sel_b  = (const int*)d_in[4];
    const int*   sel_i  = (const int*)d_in[5];
    const int*   sel_j  = (const int*)d_in[6];
    const int*   golden = (const int*)d_in[7];
    const float* W_prop = (const float*)d_in[8];
    const float* b_prop = (const float*)d_in[9];
    const float* W_in   = (const float*)d_in[10];
    const float* b_in   = (const float*)d_in[11];
    const float* W_msg  = (const float*)d_in[12];
    const float* b_msg  = (const float*)d_in[13];
    const float* W_upd  = (const float*)d_in[14];
    const float* b_upd  = (const float*)d_in[15];
    const float* W_add  = (const float*)d_in[16];
    const float* b_add  = (const float*)d_in[17];
    const float* W1     = (const float*)d_in[18];
    const float* b1     = (const float*)d_in[19];
    const float* W2     = (const float*)d_in[20];
    const float* b2     = (const float*)d_in[21];
    const float* W3     = (const float*)d_in[22];
    const float* b3     = (const float*)d_in[23];
    const float* W_out  = (const float*)d_in[24];
    const float* b_out  = (const float*)d_in[25];

    const size_t SEG = (size_t)BN * 256;
    unsigned short* P0   = (unsigned short*)d_ws;   // P even rounds; final A1
    unsigned short* P1   = P0 + SEG;                // P odd rounds
    unsigned short* hA   = P1 + SEG;                // h double-buffer; final A2
    unsigned short* hB   = hA + SEG;
    unsigned short* ETc  = hB + SEG;                // [NE][256] EDGE-ordered
    unsigned short* wbf  = ETc + (size_t)NE * 256;
    unsigned short* W_inT  = wbf;                   // [256][192]
    unsigned short* WmT    = wbf + 49152;
    unsigned short* WuaT   = WmT + 65536;
    unsigned short* WubT   = WuaT + 65536;
    unsigned short* W_addT = WubT + 65536;
    unsigned short* W1aT   = W_addT + 65536;
    unsigned short* W1bT   = W1aT + 65536;
    unsigned short* W2T    = W1bT + 65536;
    unsigned short* WfT    = W2T + 65536;           // [16][256]
    float* prop_add = (float*)(WfT + 4096);         // [64][256]
    float* bfv = prop_add + 64 * 256;               // [16]
    int* row_start = (int*)(bfv + 16);              // [4104]
    int* srcs      = row_start + 4104;              // [NE] packed src|e<<12
    int* deg       = srcs + NE;                     // [4096]
    int* rank      = deg + 4096;                    // [NE]

    // k_pre independent of CSR: runs first, zeroes deg and d_out
    k_pre<<<577, 256, 0, stream>>>(W_in, W_msg, W_upd, W_add, W1, W2, W3, b3,
                                   W_out, b_out, props, W_prop, b_prop, b_add,
                                   b_msg, eattr, wbf, WfT, bfv, prop_add,
                                   ETc, (float*)d_out, deg);
    khist_rank<<<NE / 256, 256, 0, stream>>>(eidx, deg, rank);

    // round 0 (grid 320): blocks 0-255 = h0/P0; blocks 256-319 = CSR scan+scatter
    fstep<<<320, 1024, 0, stream>>>(x, nullptr, nullptr, ETc, row_start, srcs,
                                    W_inT, nullptr, b_in, WmT, nullptr, nullptr, nullptr,
                                    hA, P0, nullptr, 0,
                                    eidx, deg, rank, srcs, row_start);
    // rounds 1..3: agg(P) -> h' -> P'
    fstep<<<256, 1024, 0, stream>>>(nullptr, hA, P0, ETc, row_start, srcs,
                                    WuaT, WubT, b_upd, WmT, nullptr, nullptr, nullptr,
                                    hB, P1, nullptr, 1,
                                    nullptr, nullptr, nullptr, nullptr, nullptr);
    fstep<<<256, 1024, 0, stream>>>(nullptr, hB, P1, ETc, row_start, srcs,
                                    WuaT, WubT, b_upd, WmT, nullptr, nullptr, nullptr,
                                    hA, P0, nullptr, 1,
                                    nullptr, nullptr, nullptr, nullptr, nullptr);
    fstep<<<256, 1024, 0, stream>>>(nullptr, hA, P0, ETc, row_start, srcs,
                                    WuaT, WubT, b_upd, WmT, nullptr, nullptr, nullptr,
                                    hB, P1, nullptr, 1,
                                    nullptr, nullptr, nullptr, nullptr, nullptr);
    // final: agg(P1) -> h4 -> embg -> A1 (P0), A2 (hA)
    fstep<<<256, 1024, 0, stream>>>(nullptr, hB, P1, ETc, row_start, srcs,
                                    WuaT, WubT, b_upd, W_addT, prop_add, W1aT, W1bT,
                                    nullptr, P0, hA, 2,
                                    nullptr, nullptr, nullptr, nullptr, nullptr);

    pair_k<<<NSEL / (64 * PTILES), 512, 0, stream>>>(P0, hA, b1, W2T, b2, WfT, bfv,
                                    sel_b, sel_i, sel_j, golden, (float*)d_out);
}